// Round 3
// baseline (230.168 us; speedup 1.0000x reference)
//
#include <hip/hip_runtime.h>

#define B_TOT 8192
#define FT    256
#define NREL  4
#define DEG   16
#define BM    16     // output rows per block; grid = 512; 512-thr blocks -> 2 blocks/CU

typedef __attribute__((ext_vector_type(8))) short bf16x8;
typedef __attribute__((ext_vector_type(4))) float f32x4;

static __device__ __forceinline__ unsigned short f2bf(float x) {
    union { float f; unsigned int u; } c; c.f = x;
    unsigned int u = c.u;
    u += 0x7fffu + ((u >> 16) & 1u);   // round-to-nearest-even
    return (unsigned short)(u >> 16);
}
static __device__ __forceinline__ float bf2f(unsigned short h) {
    union { unsigned int u; float f; } c; c.u = ((unsigned int)h) << 16;
    return c.f;
}

// ---------- kernel A: features f32 -> bf16 table (streaming, BW-floor) ----------
__global__ __launch_bounds__(256) void cvt_feat_k(const float* __restrict__ f,
                                                  unsigned short* __restrict__ fb,
                                                  int n4) {
    int i = blockIdx.x * 256 + threadIdx.x;
    if (i < n4) {
        float4 x = ((const float4*)f)[i];
        ushort4 o;
        o.x = f2bf(x.x); o.y = f2bf(x.y); o.z = f2bf(x.z); o.w = f2bf(x.w);
        ((ushort4*)fb)[i] = o;
    }
}

// ---------- kernel 0: W [4][f][o] fp32 -> Wt [4][o][f] bf16 (LDS transpose) ----------
__global__ __launch_bounds__(256) void wtrans_k(const float* __restrict__ W,
                                                unsigned short* __restrict__ Wt) {
    __shared__ float t[64][65];   // +1 pad
    int r = blockIdx.z, ft = blockIdx.y, ot = blockIdx.x;
    int c = threadIdx.x & 63, rw = threadIdx.x >> 6;
    const float* src = W + ((size_t)r * 256 + ft * 64) * 256 + ot * 64;
#pragma unroll
    for (int i = 0; i < 16; ++i) {
        int row = i * 4 + rw;
        t[row][c] = src[(size_t)row * 256 + c];
    }
    __syncthreads();
    unsigned short* dst = Wt + ((size_t)r * 256 + ot * 64) * 256 + ft * 64;
#pragma unroll
    for (int i = 0; i < 16; ++i) {
        int row = i * 4 + rw;
        dst[(size_t)row * 256 + c] = f2bf(t[c][row]);
    }
}

// ---------- fused (bf16 table): DMA gather -> LDS reduce -> MFMA -> PReLU -> rel-mean ----------
// 512 threads = 8 waves, BM=16. Wave w owns rows {2w, 2w+1} x 4 relations = 8 groups
// of 16 neighbor rows = 32 chunks of 4 rows. Each chunk: 2 global_load_lds_dwordx4
// (2 rows/instr: lanes 0-31 row A, 32-63 row B; zero data VGPRs), double-buffered
// in 2x2KB LDS slots with counted vmcnt(2). Reduce previous chunk from LDS while
// next chunk's DMA is in flight. One barrier, then GEMM (wave w -> cols [32w,32w+32)).
// MFMA convention (verified): a = A[m=lane&15][k0..k0+7], b = B[n=lane&15][k0..k0+7],
// k0 = kk*32 + (lane>>4)*8;  D elem (lane,i) -> row (lane>>4)*4+i, col lane&15.
__global__ __launch_bounds__(512, 4) void fused_dma_k(const unsigned short* __restrict__ fb,
                                                      const int* __restrict__ nidx,
                                                      const unsigned short* __restrict__ Wt,
                                                      const float* __restrict__ bias,
                                                      const float* __restrict__ prelu,
                                                      float* __restrict__ out) {
    __shared__ int shIdx[BM * NREL * DEG];            // 1024 ints, 4 KB
    __shared__ unsigned short raw[8][2][1024];        // per-wave 2x2KB DMA slots, 32 KB
    __shared__ unsigned short As[NREL][BM][FT + 8];   // 33 KB
    const int tid  = threadIdx.x;
    const int lane = tid & 63, w = tid >> 6;          // w: 0..7
    const int l32  = lane & 31, half = lane >> 5;
    const int mrow = lane & 15, quad = lane >> 4;
    const int blk  = blockIdx.x;
    const float pa = prelu[0];

    // stage this block's 1024 indices, coalesced (int2 per thread)
    ((int2*)shIdx)[tid] = ((const int2*)(nidx + (size_t)blk * (BM * NREL * DEG)))[tid];
    __syncthreads();

    const int mbase = w * 2;
    // chunk c (0..31): group g=c>>2 -> (m = mbase+(g&1), rel = g>>1), sub = c&3
    auto issue = [&](int c) {
        const int g = c >> 2, sub = c & 3;
        const int m = mbase + (g & 1), rel = g >> 1;
        const int* ib = shIdx + (m * NREL + rel) * DEG + sub * 4;
        unsigned short* slot = &raw[w][c & 1][0];
        const unsigned short* gA = fb + (size_t)ib[half]     * FT + l32 * 8;
        const unsigned short* gB = fb + (size_t)ib[2 + half] * FT + l32 * 8;
        __builtin_amdgcn_global_load_lds(
            (const __attribute__((address_space(1))) void*)gA,
            (__attribute__((address_space(3))) void*)&slot[lane * 8], 16, 0, 0);
        __builtin_amdgcn_global_load_lds(
            (const __attribute__((address_space(1))) void*)gB,
            (__attribute__((address_space(3))) void*)&slot[512 + lane * 8], 16, 0, 0);
    };

    float s0 = 0.f, s1 = 0.f, s2 = 0.f, s3 = 0.f;
    const float inv = 1.0f / 16.0f;
    issue(0);
#pragma unroll
    for (int c = 0; c < 32; ++c) {
        if (c + 1 < 32) issue(c + 1);
        // wait for chunk c's 2 loads (chunk c+1's 2 stay in flight)
        if (c + 1 < 32) asm volatile("s_waitcnt vmcnt(2)" ::: "memory");
        else            asm volatile("s_waitcnt vmcnt(0)" ::: "memory");
        if ((c & 3) == 0) { s0 = s1 = s2 = s3 = 0.f; }
        const unsigned short* slot = &raw[w][c & 1][0];
#pragma unroll
        for (int j = 0; j < 4; ++j) {
            const ushort4 x = *(const ushort4*)(slot + j * 256 + lane * 4);
            s0 += bf2f(x.x); s1 += bf2f(x.y); s2 += bf2f(x.z); s3 += bf2f(x.w);
        }
        if ((c & 3) == 3) {
            const int g = c >> 2;
            const int m = mbase + (g & 1), rel = g >> 1;
            ushort4 o;
            o.x = f2bf(s0 * inv); o.y = f2bf(s1 * inv);
            o.z = f2bf(s2 * inv); o.w = f2bf(s3 * inv);
            *(ushort4*)(&As[rel][m][lane * 4]) = o;
        }
    }
    __syncthreads();   // single barrier: As complete

    // ---- GEMM: wave w owns cols [w*32, w*32+32); B direct from L2-resident Wt ----
    const int ncol0 = w * 32 + mrow;
    f32x4 accO[2] = {};
#pragma unroll
    for (int r = 0; r < NREL; ++r) {
        const unsigned short* bp0 = Wt + ((size_t)(r * 256 + ncol0)) * FT;
        const unsigned short* bp1 = bp0 + 16 * FT;
        const float bv0 = bias[r * 256 + ncol0];
        const float bv1 = bias[r * 256 + ncol0 + 16];
        f32x4 acc[2] = {};
#pragma unroll
        for (int kk = 0; kk < 8; ++kk) {
            const int k0 = kk * 32 + quad * 8;
            const bf16x8 a  = *(const bf16x8*)(&As[r][mrow][k0]);
            const bf16x8 b0 = *(const bf16x8*)(bp0 + k0);
            const bf16x8 b1 = *(const bf16x8*)(bp1 + k0);
            acc[0] = __builtin_amdgcn_mfma_f32_16x16x32_bf16(a, b0, acc[0], 0, 0, 0);
            acc[1] = __builtin_amdgcn_mfma_f32_16x16x32_bf16(a, b1, acc[1], 0, 0, 0);
        }
#pragma unroll
        for (int i = 0; i < 4; ++i) {
            float h0 = acc[0][i] + bv0; h0 = (h0 >= 0.f) ? h0 : pa * h0;
            float h1 = acc[1][i] + bv1; h1 = (h1 >= 0.f) ? h1 : pa * h1;
            accO[0][i] += h0;
            accO[1][i] += h1;
        }
    }

    const size_t rbase = (size_t)(blk * BM + quad * 4) * 256 + ncol0;
#pragma unroll
    for (int i = 0; i < 4; ++i) {
        out[rbase + (size_t)i * 256]      = accO[0][i] * 0.25f;
        out[rbase + (size_t)i * 256 + 16] = accO[1][i] * 0.25f;
    }
}

// ---------- fallback (f32 features, register gather) — round-2 verified path ----------
__global__ __launch_bounds__(1024, 8) void fused_reg_k(const float* __restrict__ ff,
                                                       const int* __restrict__ nidx,
                                                       const unsigned short* __restrict__ Wt,
                                                       const float* __restrict__ bias,
                                                       const float* __restrict__ prelu,
                                                       float* __restrict__ out) {
    __shared__ int shIdx[BM * NREL * DEG];
    __shared__ unsigned short As[NREL][BM][FT + 8];
    const int tid  = threadIdx.x;
    const int lane = tid & 63, w = tid >> 6;
    const int blk  = blockIdx.x;
    const int mrow = lane & 15, quad = lane >> 4;
    const float pa = prelu[0];

    shIdx[tid] = nidx[(size_t)blk * (BM * NREL * DEG) + tid];
    __syncthreads();

    const float inv = 1.0f / 16.0f;
#pragma unroll
    for (int rr = 0; rr < NREL; ++rr) {
        const int* ip = shIdx + (w * NREL + rr) * DEG;
        float s0 = 0.f, s1 = 0.f, s2 = 0.f, s3 = 0.f;
#pragma unroll
        for (int h = 0; h < 2; ++h) {
            float4 x[8];
#pragma unroll
            for (int t = 0; t < 8; ++t)
                x[t] = ((const float4*)(ff + (size_t)ip[h * 8 + t] * FT))[lane];
#pragma unroll
            for (int t = 0; t < 8; ++t) {
                s0 += x[t].x; s1 += x[t].y; s2 += x[t].z; s3 += x[t].w;
            }
        }
        ushort4 o;
        o.x = f2bf(s0 * inv); o.y = f2bf(s1 * inv);
        o.z = f2bf(s2 * inv); o.w = f2bf(s3 * inv);
        *(ushort4*)(&As[rr][w][lane * 4]) = o;
    }
    __syncthreads();

    const int ncol = w * 16 + mrow;
    f32x4 accO = {};
#pragma unroll
    for (int r = 0; r < NREL; ++r) {
        const unsigned short* bp = Wt + ((size_t)(r * 256 + ncol)) * FT;
        const float bv = bias[r * 256 + ncol];
        f32x4 acc = {};
#pragma unroll
        for (int kk = 0; kk < 8; ++kk) {
            const int k0 = kk * 32 + quad * 8;
            const bf16x8 a = *(const bf16x8*)(&As[r][mrow][k0]);
            const bf16x8 b = *(const bf16x8*)(bp + k0);
            acc = __builtin_amdgcn_mfma_f32_16x16x32_bf16(a, b, acc, 0, 0, 0);
        }
#pragma unroll
        for (int i = 0; i < 4; ++i) {
            float h = acc[i] + bv;
            h = (h >= 0.f) ? h : pa * h;
            accO[i] += h;
        }
    }
    const size_t rbase = (size_t)(blk * BM + quad * 4) * 256 + ncol;
#pragma unroll
    for (int i = 0; i < 4; ++i)
        out[rbase + (size_t)i * 256] = accO[i] * 0.25f;
}

extern "C" void kernel_launch(void* const* d_in, const int* in_sizes, int n_in,
                              void* d_out, int out_size, void* d_ws, size_t ws_size,
                              hipStream_t stream) {
    const float* feat  = (const float*)d_in[0];   // [100000,256] f32
    const int*   nidx  = (const int*)  d_in[1];   // [8192,4,16] i32
    const float* W     = (const float*)d_in[2];   // [4,256,256] f32
    const float* bias  = (const float*)d_in[3];   // [4,256] f32
    const float* prelu = (const float*)d_in[4];   // [1] f32
    float* out = (float*)d_out;                   // [8192,256] f32

    const size_t feat_elems = (size_t)in_sizes[0];          // 25,600,000
    const size_t fb_bytes = feat_elems * 2;                 // 51.2 MB
    const size_t wt_bytes = (size_t)NREL * 256 * FT * 2;    // 0.5 MB

    if (ws_size >= fb_bytes + wt_bytes) {
        unsigned short* fb = (unsigned short*)d_ws;
        unsigned short* Wt = fb + feat_elems;
        int n4 = (int)(feat_elems / 4);
        cvt_feat_k<<<(n4 + 255) / 256, 256, 0, stream>>>(feat, fb, n4);
        wtrans_k<<<dim3(4, 4, 4), 256, 0, stream>>>(W, Wt);
        fused_dma_k<<<B_TOT / BM, 512, 0, stream>>>(fb, nidx, Wt, bias, prelu, out);
    } else {
        unsigned short* Wt = (unsigned short*)d_ws;
        wtrans_k<<<dim3(4, 4, 4), 256, 0, stream>>>(W, Wt);
        fused_reg_k<<<B_TOT / BM, 1024, 0, stream>>>(feat, nidx, Wt, bias, prelu, out);
    }
}

// Round 4
// 226.067 us; speedup vs baseline: 1.0181x; 1.0181x over previous
//
#include <hip/hip_runtime.h>

#define B_TOT 8192
#define FT    256
#define NREL  4
#define DEG   16
#define BM    16     // output rows per block; grid = 512; 512-thr blocks, 2 blocks/CU

typedef __attribute__((ext_vector_type(8))) short bf16x8;
typedef __attribute__((ext_vector_type(4))) float f32x4;

static __device__ __forceinline__ unsigned short f2bf(float x) {
    union { float f; unsigned int u; } c; c.f = x;
    unsigned int u = c.u;
    u += 0x7fffu + ((u >> 16) & 1u);   // round-to-nearest-even
    return (unsigned short)(u >> 16);
}
static __device__ __forceinline__ float bf2f(unsigned short h) {
    union { unsigned int u; float f; } c; c.u = ((unsigned int)h) << 16;
    return c.f;
}

// ---------- kernel A: features f32 -> bf16 table (streaming, BW-floor) ----------
__global__ __launch_bounds__(256) void cvt_feat_k(const float* __restrict__ f,
                                                  unsigned short* __restrict__ fb,
                                                  int n4) {
    int i = blockIdx.x * 256 + threadIdx.x;
    if (i < n4) {
        float4 x = ((const float4*)f)[i];
        ushort4 o;
        o.x = f2bf(x.x); o.y = f2bf(x.y); o.z = f2bf(x.z); o.w = f2bf(x.w);
        ((ushort4*)fb)[i] = o;
    }
}

// ---------- kernel 0: W [4][f][o] fp32 -> Wt [4][o][f] bf16 (LDS transpose) ----------
__global__ __launch_bounds__(256) void wtrans_k(const float* __restrict__ W,
                                                unsigned short* __restrict__ Wt) {
    __shared__ float t[64][65];   // +1 pad
    int r = blockIdx.z, ft = blockIdx.y, ot = blockIdx.x;
    int c = threadIdx.x & 63, rw = threadIdx.x >> 6;
    const float* src = W + ((size_t)r * 256 + ft * 64) * 256 + ot * 64;
#pragma unroll
    for (int i = 0; i < 16; ++i) {
        int row = i * 4 + rw;
        t[row][c] = src[(size_t)row * 256 + c];
    }
    __syncthreads();
    unsigned short* dst = Wt + ((size_t)r * 256 + ot * 64) * 256 + ft * 64;
#pragma unroll
    for (int i = 0; i < 16; ++i) {
        int row = i * 4 + rw;
        dst[(size_t)row * 256 + c] = f2bf(t[c][row]);
    }
}

// ---------- fused: deep register gather -> LDS -> MFMA -> PReLU -> rel-mean ----------
// 512 threads = 8 waves, BM=16, grid 512, launch_bounds(512,4) -> 128 VGPR budget.
// Wave w owns 8 (m,rel) tasks: g = w*8+t, m = g>>2, rel = g&3. Per task: 16
// INDEPENDENT ushort4 row-loads into a statically-indexed register batch, with a
// sched_barrier(0) pinning all 16 issues BEFORE the reduce (prevents the
// live-range-minimizing interleave that serialized round 2 at VGPR=32).
// 16 waves/CU x 16 rows in flight = 256 rows/CU of MLP.
// One barrier, then per-wave GEMM: wave w -> cols [32w, 32w+32), B from L2 Wt.
// MFMA convention (verified): a = A[m=lane&15][k0..k0+7], b = B[n=lane&15][k0..k0+7],
// k0 = kk*32 + (lane>>4)*8;  D elem (lane,i) -> row (lane>>4)*4+i, col lane&15.
__global__ __launch_bounds__(512, 4) void fused_k(const unsigned short* __restrict__ fb,
                                                  const int* __restrict__ nidx,
                                                  const unsigned short* __restrict__ Wt,
                                                  const float* __restrict__ bias,
                                                  const float* __restrict__ prelu,
                                                  float* __restrict__ out) {
    __shared__ int shIdx[BM * NREL * DEG];            // 1024 ints, 4 KB
    __shared__ unsigned short As[NREL][BM][FT + 8];   // 33 KB; 16B-slot stride 33 == 1 mod 32 -> conflict-free b128 reads
    const int tid  = threadIdx.x;
    const int lane = tid & 63, w = tid >> 6;          // w: 0..7
    const int mrow = lane & 15, quad = lane >> 4;
    const int blk  = blockIdx.x;
    const float pa = prelu[0];

    // stage this block's 1024 indices, coalesced (int2 per thread)
    ((int2*)shIdx)[tid] = ((const int2*)(nidx + (size_t)blk * (BM * NREL * DEG)))[tid];
    __syncthreads();

    const float inv = 1.0f / 16.0f;
#pragma unroll
    for (int t = 0; t < 8; ++t) {
        const int g   = w * 8 + t;          // task id: m = g>>2, rel = g&3, (m*NREL+rel)==g
        const int m   = g >> 2, rel = g & 3;
        const int* ip = shIdx + g * DEG;
        const int4 i0 = *(const int4*)(ip);
        const int4 i1 = *(const int4*)(ip + 4);
        const int4 i2 = *(const int4*)(ip + 8);
        const int4 i3 = *(const int4*)(ip + 12);
        int idx[DEG] = { i0.x, i0.y, i0.z, i0.w, i1.x, i1.y, i1.z, i1.w,
                         i2.x, i2.y, i2.z, i2.w, i3.x, i3.y, i3.z, i3.w };
        ushort4 x[DEG];                      // 32 VGPRs of data, statically indexed
#pragma unroll
        for (int j = 0; j < DEG; ++j)
            x[j] = *(const ushort4*)(fb + (size_t)idx[j] * FT + lane * 4);
        __builtin_amdgcn_sched_barrier(0);   // all 16 loads issued before any add
        float s0 = 0.f, s1 = 0.f, s2 = 0.f, s3 = 0.f;
#pragma unroll
        for (int j = 0; j < DEG; ++j) {
            s0 += bf2f(x[j].x); s1 += bf2f(x[j].y);
            s2 += bf2f(x[j].z); s3 += bf2f(x[j].w);
        }
        ushort4 o;
        o.x = f2bf(s0 * inv); o.y = f2bf(s1 * inv);
        o.z = f2bf(s2 * inv); o.w = f2bf(s3 * inv);
        *(ushort4*)(&As[rel][m][lane * 4]) = o;
    }
    __syncthreads();   // single barrier: As complete

    // ---- GEMM: wave w owns cols [w*32, w*32+32); B direct from L2-resident Wt ----
    const int ncol0 = w * 32 + mrow;
    f32x4 accO[2] = {};
#pragma unroll
    for (int r = 0; r < NREL; ++r) {
        const unsigned short* bp0 = Wt + ((size_t)(r * 256 + ncol0)) * FT;
        const unsigned short* bp1 = bp0 + 16 * FT;
        const float bv0 = bias[r * 256 + ncol0];
        const float bv1 = bias[r * 256 + ncol0 + 16];
        f32x4 acc[2] = {};
#pragma unroll
        for (int kk = 0; kk < 8; ++kk) {
            const int k0 = kk * 32 + quad * 8;
            const bf16x8 a  = *(const bf16x8*)(&As[r][mrow][k0]);
            const bf16x8 b0 = *(const bf16x8*)(bp0 + k0);
            const bf16x8 b1 = *(const bf16x8*)(bp1 + k0);
            acc[0] = __builtin_amdgcn_mfma_f32_16x16x32_bf16(a, b0, acc[0], 0, 0, 0);
            acc[1] = __builtin_amdgcn_mfma_f32_16x16x32_bf16(a, b1, acc[1], 0, 0, 0);
        }
#pragma unroll
        for (int i = 0; i < 4; ++i) {
            float h0 = acc[0][i] + bv0; h0 = (h0 >= 0.f) ? h0 : pa * h0;
            float h1 = acc[1][i] + bv1; h1 = (h1 >= 0.f) ? h1 : pa * h1;
            accO[0][i] += h0;
            accO[1][i] += h1;
        }
    }

    const size_t rbase = (size_t)(blk * BM + quad * 4) * 256 + ncol0;
#pragma unroll
    for (int i = 0; i < 4; ++i) {
        out[rbase + (size_t)i * 256]      = accO[0][i] * 0.25f;
        out[rbase + (size_t)i * 256 + 16] = accO[1][i] * 0.25f;
    }
}

// ---------- fallback (f32 features, register gather) — round-2 verified path ----------
__global__ __launch_bounds__(1024, 8) void fused_reg_k(const float* __restrict__ ff,
                                                       const int* __restrict__ nidx,
                                                       const unsigned short* __restrict__ Wt,
                                                       const float* __restrict__ bias,
                                                       const float* __restrict__ prelu,
                                                       float* __restrict__ out) {
    __shared__ int shIdx[BM * NREL * DEG];
    __shared__ unsigned short As[NREL][BM][FT + 8];
    const int tid  = threadIdx.x;
    const int lane = tid & 63, w = tid >> 6;
    const int blk  = blockIdx.x;
    const int mrow = lane & 15, quad = lane >> 4;
    const float pa = prelu[0];

    shIdx[tid] = nidx[(size_t)blk * (BM * NREL * DEG) + tid];
    __syncthreads();

    const float inv = 1.0f / 16.0f;
#pragma unroll
    for (int rr = 0; rr < NREL; ++rr) {
        const int* ip = shIdx + (w * NREL + rr) * DEG;
        float s0 = 0.f, s1 = 0.f, s2 = 0.f, s3 = 0.f;
#pragma unroll
        for (int h = 0; h < 2; ++h) {
            float4 x[8];
#pragma unroll
            for (int t = 0; t < 8; ++t)
                x[t] = ((const float4*)(ff + (size_t)ip[h * 8 + t] * FT))[lane];
#pragma unroll
            for (int t = 0; t < 8; ++t) {
                s0 += x[t].x; s1 += x[t].y; s2 += x[t].z; s3 += x[t].w;
            }
        }
        ushort4 o;
        o.x = f2bf(s0 * inv); o.y = f2bf(s1 * inv);
        o.z = f2bf(s2 * inv); o.w = f2bf(s3 * inv);
        *(ushort4*)(&As[rr][w][lane * 4]) = o;
    }
    __syncthreads();

    const int ncol = w * 16 + mrow;
    f32x4 accO = {};
#pragma unroll
    for (int r = 0; r < NREL; ++r) {
        const unsigned short* bp = Wt + ((size_t)(r * 256 + ncol)) * FT;
        const float bv = bias[r * 256 + ncol];
        f32x4 acc = {};
#pragma unroll
        for (int kk = 0; kk < 8; ++kk) {
            const int k0 = kk * 32 + quad * 8;
            const bf16x8 a = *(const bf16x8*)(&As[r][mrow][k0]);
            const bf16x8 b = *(const bf16x8*)(bp + k0);
            acc = __builtin_amdgcn_mfma_f32_16x16x32_bf16(a, b, acc, 0, 0, 0);
        }
#pragma unroll
        for (int i = 0; i < 4; ++i) {
            float h = acc[i] + bv;
            h = (h >= 0.f) ? h : pa * h;
            accO[i] += h;
        }
    }
    const size_t rbase = (size_t)(blk * BM + quad * 4) * 256 + ncol;
#pragma unroll
    for (int i = 0; i < 4; ++i)
        out[rbase + (size_t)i * 256] = accO[i] * 0.25f;
}

extern "C" void kernel_launch(void* const* d_in, const int* in_sizes, int n_in,
                              void* d_out, int out_size, void* d_ws, size_t ws_size,
                              hipStream_t stream) {
    const float* feat  = (const float*)d_in[0];   // [100000,256] f32
    const int*   nidx  = (const int*)  d_in[1];   // [8192,4,16] i32
    const float* W     = (const float*)d_in[2];   // [4,256,256] f32
    const float* bias  = (const float*)d_in[3];   // [4,256] f32
    const float* prelu = (const float*)d_in[4];   // [1] f32
    float* out = (float*)d_out;                   // [8192,256] f32

    const size_t feat_elems = (size_t)in_sizes[0];          // 25,600,000
    const size_t fb_bytes = feat_elems * 2;                 // 51.2 MB
    const size_t wt_bytes = (size_t)NREL * 256 * FT * 2;    // 0.5 MB

    if (ws_size >= fb_bytes + wt_bytes) {
        unsigned short* fb = (unsigned short*)d_ws;
        unsigned short* Wt = fb + feat_elems;
        int n4 = (int)(feat_elems / 4);
        cvt_feat_k<<<(n4 + 255) / 256, 256, 0, stream>>>(feat, fb, n4);
        wtrans_k<<<dim3(4, 4, 4), 256, 0, stream>>>(W, Wt);
        fused_k<<<B_TOT / BM, 512, 0, stream>>>(fb, nidx, Wt, bias, prelu, out);
    } else {
        unsigned short* Wt = (unsigned short*)d_ws;
        wtrans_k<<<dim3(4, 4, 4), 256, 0, stream>>>(W, Wt);
        fused_reg_k<<<B_TOT / BM, 1024, 0, stream>>>(feat, nidx, Wt, bias, prelu, out);
    }
}